// Round 17
// baseline (101.360 us; speedup 1.0000x reference)
//
#include <hip/hip_runtime.h>
#include <math.h>

// NoisyTopkRouter: B=4,S=4096,D=2048,E=64,TOP_K=8
//   convert_w   : W -> per-K-block bf16 hi/lo LDS-image, baked swizzle [frozen]
//   gemm_k1     : 32x128 tile, mfma 32x32x16, SPLIT-K=2, counted-vmcnt
//                 pipeline: 4 LDS buffers, DMA 3 steps ahead, raw s_barrier +
//                 s_waitcnt vmcnt(10/5/0) (r16's __syncthreads drained vmcnt(0)
//                 every step -> paid full DMA latency per step; T3/T4 fix).
//                 All staging via global_load_lds (B 4 + x 1 instr/thread,
//                 uniform); x bsplit moved to consume side.
//   epi_fast    : one wave/token fast path (+2-way partial sum)      [frozen]
//   refine_dots : one WAVE per (flagged token, expert) fp64 dots     [frozen]
//   refine_final: one wave per flagged token fp64 softmax/top-8      [frozen]

#define KDIM 2048
#define NEXP 64
#define BM 32
#define KB 32
#define KSPLIT 2
#define NKBH (KDIM / KB / KSPLIT)   // 32 K-blocks per half
#define TAU 1.5e-4f

typedef __attribute__((ext_vector_type(8))) short short8v;
typedef __attribute__((ext_vector_type(16))) float f32x16;

__device__ __forceinline__ void bsplit(float v, ushort& h, ushort& l) {
  unsigned u = __float_as_uint(v);
  unsigned hu = (u + 0x8000u) & 0xFFFF0000u;
  h = (ushort)(hu >> 16);
  float r = v - __uint_as_float(hu);
  l = (ushort)((__float_as_uint(r) + 0x8000u) >> 16);
}

// Wpk[blk 0..63][col 0..127][unit' 0..7][8 bf16]; unit' = (p*4+u) ^ (col&7)
__global__ __launch_bounds__(256)
void convert_w(const float* __restrict__ Wr, const float* __restrict__ Wn,
               ushort* __restrict__ Wpk, int* __restrict__ flagcnt) {
  if (blockIdx.x == 0 && threadIdx.x == 0) *flagcnt = 0;
  const int g = blockIdx.x * 256 + threadIdx.x;   // 32768 threads
  const int col = g >> 8;                         // 0..127
  const int rem = g & 255;
  const int blk = rem >> 2;                       // 0..63 K-block
  const int u   = rem & 3;                        // k-unit (8 elems)
  const float* srcrow = (col < NEXP) ? (Wr + (size_t)col * KDIM)
                                     : (Wn + (size_t)(col - NEXP) * KDIM);
  const int k = blk * 32 + u * 8;
  const float4 v0 = *(const float4*)(srcrow + k);
  const float4 v1 = *(const float4*)(srcrow + k + 4);
  short8v hv, lv; ushort h, l;
  bsplit(v0.x, h, l); hv[0] = h; lv[0] = l;
  bsplit(v0.y, h, l); hv[1] = h; lv[1] = l;
  bsplit(v0.z, h, l); hv[2] = h; lv[2] = l;
  bsplit(v0.w, h, l); hv[3] = h; lv[3] = l;
  bsplit(v1.x, h, l); hv[4] = h; lv[4] = l;
  bsplit(v1.y, h, l); hv[5] = h; lv[5] = l;
  bsplit(v1.z, h, l); hv[6] = h; lv[6] = l;
  bsplit(v1.w, h, l); hv[7] = h; lv[7] = l;
  const size_t base = (size_t)blk * 8192 + (size_t)col * 64;
  *(short8v*)(Wpk + base + (size_t)((u)     ^ (col & 7)) * 8) = hv;
  *(short8v*)(Wpk + base + (size_t)((4 + u) ^ (col & 7)) * 8) = lv;
}

__global__ __launch_bounds__(256, 2)
void gemm_k1(const float* __restrict__ x, const ushort* __restrict__ Wpk,
             float* __restrict__ partials)   // [KSPLIT][M][128]
{
  __shared__ ushort Bb[4][8192];   // 4 x 16KB
  __shared__ float  Xb[4][1024];   // 4 x  4KB  [row32][slot'8][4 f32]

  const int tid  = threadIdx.x;
  const int row0 = blockIdx.x * BM;
  const int ks   = blockIdx.y;
  const ushort* Wpkh = Wpk + (size_t)ks * NKBH * 8192;
  const int M = gridDim.x * BM;

  const int wid  = tid >> 6;
  const int lane = tid & 63;
  const int l31  = lane & 31;
  const int kg   = lane >> 5;

  // x DMA source map (source-swizzled so linear LDS dest reads conflict-free)
  const int xrow_l = 8 * wid + (lane >> 3);            // row this lane stages
  const int xslotp = lane & 7;                         // dest slot'
  const int xslot  = xslotp ^ (xrow_l & 7);            // src slot
  const float* xg = x + (size_t)(row0 + xrow_l) * KDIM
                      + (size_t)ks * (KDIM / KSPLIT) + xslot * 4;

  // B fragment constants (r16 layout, frozen)
  const int colB = wid * 32 + l31;
  const int fb   = colB & 7;
  const int e_a  = l31 & 7;                            // A slot swizzle key

  f32x16 acc = {0,0,0,0, 0,0,0,0, 0,0,0,0, 0,0,0,0};

#define ISSUE_STEP(t, b)                                                      \
  do {                                                                        \
    _Pragma("unroll")                                                         \
    for (int j = 0; j < 4; ++j) {                                             \
      __builtin_amdgcn_global_load_lds(                                       \
          (const __attribute__((address_space(1))) void*)                     \
              (Wpkh + (size_t)(t) * 8192 + (size_t)(j * 256 + tid) * 8),      \
          (__attribute__((address_space(3))) void*)                           \
              (&Bb[b][(size_t)(j * 256 + tid) * 8]), 16, 0, 0);               \
    }                                                                         \
    __builtin_amdgcn_global_load_lds(                                         \
        (const __attribute__((address_space(1))) void*)(xg + (size_t)(t)*32), \
        (__attribute__((address_space(3))) void*)(&Xb[b][tid * 4]),           \
        16, 0, 0);                                                            \
  } while (0)

  // prologue: 3 batches in flight, wait batch 0 home (outstanding = 10)
  ISSUE_STEP(0, 0);
  ISSUE_STEP(1, 1);
  ISSUE_STEP(2, 2);
  asm volatile("s_waitcnt vmcnt(10)" ::: "memory");
  __builtin_amdgcn_s_barrier();
  __builtin_amdgcn_sched_barrier(0);

  for (int s = 0; s < NKBH; ++s) {
    const int cur = s & 3;
    if (s + 3 < NKBH) ISSUE_STEP(s + 3, (s + 3) & 3);

    // ---- compute K-block s from buf[cur] ----
#pragma unroll
    for (int kk = 0; kk < 2; ++kk) {
      const int u = kk * 2 + kg;
      // A: read 8 f32 (slots (2u)^e, (2u+1)^e), split on the fly
      const float4 va = *(const float4*)&Xb[cur][(l31 * 8 + ((2 * u) ^ e_a)) * 4];
      const float4 vb = *(const float4*)&Xb[cur][(l31 * 8 + ((2 * u + 1) ^ e_a)) * 4];
      short8v ah, al; ushort h, l;
      bsplit(va.x, h, l); ah[0] = h; al[0] = l;
      bsplit(va.y, h, l); ah[1] = h; al[1] = l;
      bsplit(va.z, h, l); ah[2] = h; al[2] = l;
      bsplit(va.w, h, l); ah[3] = h; al[3] = l;
      bsplit(vb.x, h, l); ah[4] = h; al[4] = l;
      bsplit(vb.y, h, l); ah[5] = h; al[5] = l;
      bsplit(vb.z, h, l); ah[6] = h; al[6] = l;
      bsplit(vb.w, h, l); ah[7] = h; al[7] = l;
      const short8v bh = *(const short8v*)&Bb[cur][colB * 64 + ((u)     ^ fb) * 8];
      const short8v bl = *(const short8v*)&Bb[cur][colB * 64 + ((4 + u) ^ fb) * 8];
      acc = __builtin_amdgcn_mfma_f32_32x32x16_bf16(ah, bh, acc, 0, 0, 0);
      acc = __builtin_amdgcn_mfma_f32_32x32x16_bf16(ah, bl, acc, 0, 0, 0);
      acc = __builtin_amdgcn_mfma_f32_32x32x16_bf16(al, bh, acc, 0, 0, 0);
    }

    // ---- counted drain: ensure step s+1's batch is home, then barrier ----
    __builtin_amdgcn_sched_barrier(0);
    const int ahead = NKBH - 1 - s;
    if (ahead >= 3) {
      asm volatile("s_waitcnt vmcnt(10)" ::: "memory");
    } else if (ahead == 2) {
      asm volatile("s_waitcnt vmcnt(5)" ::: "memory");
    } else if (ahead == 1) {
      asm volatile("s_waitcnt vmcnt(0)" ::: "memory");
    }
    __builtin_amdgcn_s_barrier();
    __builtin_amdgcn_sched_barrier(0);
  }
#undef ISSUE_STEP

  // C/D layout (32x32): col = lane&31, row = (reg&3) + 8*(reg>>2) + 4*kg
  float* dst = partials + (size_t)ks * M * 128;
#pragma unroll
  for (int reg = 0; reg < 16; ++reg) {
    const int row = (reg & 3) + 8 * (reg >> 2) + 4 * kg;
    dst[(size_t)(row0 + row) * 128 + colB] = acc[reg];
  }
}

// one wave per token: fast path; sums the KSPLIT partials inline
__global__ __launch_bounds__(512, 4)
void epi_fast(const float* __restrict__ partials, int M,
              const float* __restrict__ br, const float* __restrict__ bn,
              const float* __restrict__ noise,
              float* __restrict__ out_w, float* __restrict__ out_i,
              float* __restrict__ out_s,
              int* __restrict__ flagcnt, int* __restrict__ flaglist)
{
  const int wid  = threadIdx.x >> 6;
  const int lane = threadIdx.x & 63;
  const int t    = blockIdx.x * 8 + wid;

  const float sr = partials[(size_t)t * 128 + lane]
                 + partials[(size_t)M * 128 + (size_t)t * 128 + lane];
  const float sn = partials[(size_t)t * 128 + 64 + lane]
                 + partials[(size_t)M * 128 + (size_t)t * 128 + 64 + lane];
  const float z  = sn + bn[lane];
  const float sp = fmaxf(z, 0.f) + log1pf(expf(-fabsf(z)));
  const float v  = sr + br[lane] + noise[(size_t)t * NEXP + lane] * sp;

  float m = v;
#pragma unroll
  for (int d = 32; d; d >>= 1) m = fmaxf(m, __shfl_xor(m, d));
  const float p = expf(v - m);
  float sum = p;
#pragma unroll
  for (int d = 32; d; d >>= 1) sum += __shfl_xor(sum, d);
  out_s[(size_t)t * NEXP + lane] = p / sum;

  float cur = v;
  float vals9[9]; int idx9[9];
#pragma unroll
  for (int it = 0; it < 9; ++it) {
    float mx = cur;
#pragma unroll
    for (int d = 32; d; d >>= 1) mx = fmaxf(mx, __shfl_xor(mx, d));
    const unsigned long long b = __ballot(cur == mx);
    const int li = __ffsll(b) - 1;                 // ties -> lowest index
    vals9[it] = mx; idx9[it] = li;
    if (lane == li) cur = -INFINITY;
  }
  bool flagged = false;
#pragma unroll
  for (int q = 0; q < 8; ++q) flagged |= (vals9[q] - vals9[q + 1] < TAU);

  if (flagged) {
    if (lane == 0) {
      const int s = atomicAdd(flagcnt, 1);
      flaglist[s] = t;
    }
    return;                                        // refine_* writes outputs
  }

  float pt[8]; float ws = 0.f;
#pragma unroll
  for (int q = 0; q < 8; ++q) { pt[q] = expf(vals9[q] - m); ws += pt[q]; }
  if (lane < 8) {
    out_w[(size_t)t * 8 + lane] = pt[lane] / ws;
    out_i[(size_t)t * 8 + lane] = (float)idx9[lane];
  }
}

// one WAVE per (flagged token, expert): nf*64 wave-jobs, grid-strided
__global__ __launch_bounds__(512)
void refine_dots(const float* __restrict__ x,
                 const float* __restrict__ Wr, const float* __restrict__ Wn,
                 const float* __restrict__ br, const float* __restrict__ bn,
                 const float* __restrict__ noise,
                 const int* __restrict__ flagcnt, const int* __restrict__ flaglist,
                 double* __restrict__ nv64)
{
  const int nf    = *flagcnt;
  const int lane  = threadIdx.x & 63;
  const int wslot = (blockIdx.x * 512 + threadIdx.x) >> 6;
  const int nwav  = (gridDim.x * 512) >> 6;
  const int total = nf * 64;

  for (int w = wslot; w < total; w += nwav) {
    const int i = w >> 6, e = w & 63;
    const int t = flaglist[i];
    const float* xr  = x  + (size_t)t * KDIM + lane * 4;
    const float* wrr = Wr + (size_t)e * KDIM + lane * 4;
    const float* wnr = Wn + (size_t)e * KDIM + lane * 4;
    double a0 = 0, a1 = 0, c0 = 0, c1 = 0;
#pragma unroll
    for (int q = 0; q < 8; ++q) {
      const float4 xv = *(const float4*)(xr  + q * 256);
      const float4 wv = *(const float4*)(wrr + q * 256);
      const float4 nv = *(const float4*)(wnr + q * 256);
      a0 = fma((double)xv.x, (double)wv.x, a0);
      a1 = fma((double)xv.y, (double)wv.y, a1);
      a0 = fma((double)xv.z, (double)wv.z, a0);
      a1 = fma((double)xv.w, (double)wv.w, a1);
      c0 = fma((double)xv.x, (double)nv.x, c0);
      c1 = fma((double)xv.y, (double)nv.y, c1);
      c0 = fma((double)xv.z, (double)nv.z, c0);
      c1 = fma((double)xv.w, (double)nv.w, c1);
    }
    double ar = a0 + a1, an = c0 + c1;
#pragma unroll
    for (int d = 32; d; d >>= 1) {
      ar += __shfl_xor(ar, d);
      an += __shfl_xor(an, d);
    }
    if (lane == 0) {
      const double rte = ar + (double)br[e];
      const double zz  = an + (double)bn[e];
      const double spd = fmax(zz, 0.0) + log1p(exp(-fabs(zz)));
      nv64[(size_t)i * 64 + e] = rte + (double)noise[(size_t)t * NEXP + e] * spd;
    }
  }
}

// one wave per flagged token: proven fp64 softmax/top-8 tail
__global__ __launch_bounds__(512)
void refine_final(const double* __restrict__ nv64,
                  const int* __restrict__ flagcnt, const int* __restrict__ flaglist,
                  float* __restrict__ out_w, float* __restrict__ out_i,
                  float* __restrict__ out_s)
{
  const int nf    = *flagcnt;
  const int lane  = threadIdx.x & 63;
  const int wslot = (blockIdx.x * 512 + threadIdx.x) >> 6;
  const int nwav  = (gridDim.x * 512) >> 6;

  for (int i = wslot; i < nf; i += nwav) {
    const int t = flaglist[i];
    const double v64 = nv64[(size_t)i * 64 + lane];
    double md = v64;
#pragma unroll
    for (int d = 32; d; d >>= 1) md = fmax(md, __shfl_xor(md, d));
    const double pe = exp(v64 - md);
    double sd = pe;
#pragma unroll
    for (int d = 32; d; d >>= 1) sd += __shfl_xor(sd, d);
    out_s[(size_t)t * NEXP + lane] = (float)(pe / sd);

    double curd = v64;
    double pv8[8]; int pi8[8]; double wsd = 0.0;
#pragma unroll
    for (int it = 0; it < 8; ++it) {
      double mx = curd;
#pragma unroll
      for (int d = 32; d; d >>= 1) mx = fmax(mx, __shfl_xor(mx, d));
      const unsigned long long b = __ballot(curd == mx);
      const int li = __ffsll(b) - 1;
      pv8[it] = __shfl(pe, li); pi8[it] = li; wsd += pv8[it];
      if (lane == li) curd = -1e300;
    }
    if (lane < 8) {
      out_w[(size_t)t * 8 + lane] = (float)(pv8[lane] / wsd);
      out_i[(size_t)t * 8 + lane] = (float)pi8[lane];
    }
  }
}

extern "C" void kernel_launch(void* const* d_in, const int* in_sizes, int n_in,
                              void* d_out, int out_size, void* d_ws, size_t ws_size,
                              hipStream_t stream) {
  const float* x     = (const float*)d_in[0];
  const float* Wr    = (const float*)d_in[1];
  const float* br    = (const float*)d_in[2];
  const float* Wn    = (const float*)d_in[3];
  const float* bn    = (const float*)d_in[4];
  const float* noise = (const float*)d_in[5];

  const int M = in_sizes[0] / KDIM;                  // 16384 tokens
  float*  partials = (float*)d_ws;                   // [2][M][128] f32 = 16 MB
  double* nv64     = (double*)d_ws;                  // aliases partials (dead
                                                     // after epi_fast)
  ushort* Wpk      = (ushort*)(partials + (size_t)KSPLIT * M * 128);  // 1 MB
  int*    flagcnt  = (int*)(Wpk + (size_t)64 * 8192);
  int*    flaglist = flagcnt + 1;                    // up to M ints

  float* out   = (float*)d_out;
  float* out_w = out;                                // [M,8]
  float* out_i = out + (size_t)M * 8;                // [M,8] indices as floats
  float* out_s = out + (size_t)M * 16;               // [M,64]

  convert_w<<<dim3(128), dim3(256), 0, stream>>>(Wr, Wn, Wpk, flagcnt);
  gemm_k1<<<dim3(M / BM, KSPLIT), dim3(256), 0, stream>>>(x, Wpk, partials);
  epi_fast<<<dim3(M / 8), dim3(512), 0, stream>>>(partials, M, br, bn, noise,
                                                  out_w, out_i, out_s,
                                                  flagcnt, flaglist);
  refine_dots<<<dim3(1024), dim3(512), 0, stream>>>(x, Wr, Wn, br, bn, noise,
                                                    flagcnt, flaglist, nv64);
  refine_final<<<dim3(256), dim3(512), 0, stream>>>(nv64, flagcnt, flaglist,
                                                    out_w, out_i, out_s);
}

// Round 18
// 84.648 us; speedup vs baseline: 1.1974x; 1.1974x over previous
//
#include <hip/hip_runtime.h>
#include <math.h>

// NoisyTopkRouter: B=4,S=4096,D=2048,E=64,TOP_K=8
//   convert_w   : W -> per-K-block bf16 hi/lo LDS-image, baked swizzle [frozen]
//   gemm_k1     : r18: BM=64, wave tile 64x32 (M_rep=2) -> 6 MFMA per 6 LDS
//                 reads (was 3 per 4) and 64 steps/CU (was 128). r16 skeleton:
//                 B via global_load_lds, A reg->bsplit->swizzled ds_write,
//                 dbuf, __syncthreads. (r17 counted-vmcnt reverted: it halved
//                 occupancy + put bsplit on the MFMA critical path.)
//   epi_fast    : one wave/token fast path (+2-way partial sum)      [frozen]
//   refine_dots : one WAVE per (flagged token, expert) fp64 dots     [frozen]
//   refine_final: one wave per flagged token fp64 softmax/top-8      [frozen]

#define KDIM 2048
#define NEXP 64
#define BM 64
#define KB 32
#define KSPLIT 2
#define NKBH (KDIM / KB / KSPLIT)   // 32 K-blocks per half
#define TAU 1.5e-4f

typedef __attribute__((ext_vector_type(8))) short short8v;
typedef __attribute__((ext_vector_type(16))) float f32x16;

__device__ __forceinline__ void bsplit(float v, ushort& h, ushort& l) {
  unsigned u = __float_as_uint(v);
  unsigned hu = (u + 0x8000u) & 0xFFFF0000u;
  h = (ushort)(hu >> 16);
  float r = v - __uint_as_float(hu);
  l = (ushort)((__float_as_uint(r) + 0x8000u) >> 16);
}

// Wpk[blk 0..63][col 0..127][unit' 0..7][8 bf16]; unit' = (p*4+u) ^ (col&7)
__global__ __launch_bounds__(256)
void convert_w(const float* __restrict__ Wr, const float* __restrict__ Wn,
               ushort* __restrict__ Wpk, int* __restrict__ flagcnt) {
  if (blockIdx.x == 0 && threadIdx.x == 0) *flagcnt = 0;
  const int g = blockIdx.x * 256 + threadIdx.x;   // 32768 threads
  const int col = g >> 8;                         // 0..127
  const int rem = g & 255;
  const int blk = rem >> 2;                       // 0..63 K-block
  const int u   = rem & 3;                        // k-unit (8 elems)
  const float* srcrow = (col < NEXP) ? (Wr + (size_t)col * KDIM)
                                     : (Wn + (size_t)(col - NEXP) * KDIM);
  const int k = blk * 32 + u * 8;
  const float4 v0 = *(const float4*)(srcrow + k);
  const float4 v1 = *(const float4*)(srcrow + k + 4);
  short8v hv, lv; ushort h, l;
  bsplit(v0.x, h, l); hv[0] = h; lv[0] = l;
  bsplit(v0.y, h, l); hv[1] = h; lv[1] = l;
  bsplit(v0.z, h, l); hv[2] = h; lv[2] = l;
  bsplit(v0.w, h, l); hv[3] = h; lv[3] = l;
  bsplit(v1.x, h, l); hv[4] = h; lv[4] = l;
  bsplit(v1.y, h, l); hv[5] = h; lv[5] = l;
  bsplit(v1.z, h, l); hv[6] = h; lv[6] = l;
  bsplit(v1.w, h, l); hv[7] = h; lv[7] = l;
  const size_t base = (size_t)blk * 8192 + (size_t)col * 64;
  *(short8v*)(Wpk + base + (size_t)((u)     ^ (col & 7)) * 8) = hv;
  *(short8v*)(Wpk + base + (size_t)((4 + u) ^ (col & 7)) * 8) = lv;
}

__global__ __launch_bounds__(256, 2)
void gemm_k1(const float* __restrict__ x, const ushort* __restrict__ Wpk,
             float* __restrict__ partials)   // [KSPLIT][M][128]
{
  __shared__ ushort Bb[2][8192];   // 2 x 16KB  [col128][unit'8][8]
  __shared__ ushort Ab[2][4096];   // 2 x  8KB  [row64][unit'8][8]

  const int tid  = threadIdx.x;
  const int row0 = blockIdx.x * BM;
  const int ks   = blockIdx.y;                       // K-half 0/1
  const ushort* Wpkh = Wpk + (size_t)ks * NKBH * 8192;
  const int M = gridDim.x * BM;

  const int wid  = tid >> 6;           // col-way 0..3
  const int lane = tid & 63;
  const int l31  = lane & 31;
  const int kg   = lane >> 5;

  // A stage map: srow = tid>>2 (0..63), su = tid&3 (k-unit) — all 256 threads
  const int srow = tid >> 2;
  const int su   = tid & 3;
  const float* xrow = x + (size_t)(row0 + srow) * KDIM
                        + (size_t)ks * (KDIM / KSPLIT) + su * 8;
  const int fw   = ((srow & 1) << 2) | ((srow >> 1) & 3);
  const int aoff_h = srow * 64 + ((su)     ^ fw) * 8;
  const int aoff_l = srow * 64 + ((4 + su) ^ fw) * 8;

  // fragment read constants
  const int fa   = ((l31 & 1) << 2) | ((l31 >> 1) & 3);  // same for both row-groups
  const int colB = wid * 32 + l31;
  const int fb   = colB & 7;

  f32x16 accA = {0,0,0,0, 0,0,0,0, 0,0,0,0, 0,0,0,0};   // rows +0..31
  f32x16 accB = {0,0,0,0, 0,0,0,0, 0,0,0,0, 0,0,0,0};   // rows +32..63

  // prologue: stage K-block 0
#pragma unroll
  for (int j = 0; j < 4; ++j) {
    const int idx = j * 256 + tid;
    __builtin_amdgcn_global_load_lds(
        (const __attribute__((address_space(1))) void*)(Wpkh + (size_t)idx * 8),
        (__attribute__((address_space(3))) void*)(&Bb[0][(size_t)idx * 8]),
        16, 0, 0);
  }
  {
    const float4 xa = *(const float4*)(xrow);
    const float4 xb = *(const float4*)(xrow + 4);
    short8v hv, lv; ushort h, l;
    bsplit(xa.x, h, l); hv[0] = h; lv[0] = l;
    bsplit(xa.y, h, l); hv[1] = h; lv[1] = l;
    bsplit(xa.z, h, l); hv[2] = h; lv[2] = l;
    bsplit(xa.w, h, l); hv[3] = h; lv[3] = l;
    bsplit(xb.x, h, l); hv[4] = h; lv[4] = l;
    bsplit(xb.y, h, l); hv[5] = h; lv[5] = l;
    bsplit(xb.z, h, l); hv[6] = h; lv[6] = l;
    bsplit(xb.w, h, l); hv[7] = h; lv[7] = l;
    *(short8v*)&Ab[0][aoff_h] = hv;
    *(short8v*)&Ab[0][aoff_l] = lv;
  }
  __syncthreads();

  for (int s = 0; s < NKBH; ++s) {
    const int cur = s & 1, nxt = cur ^ 1;
    float4 xa, xb;
    if (s + 1 < NKBH) {
#pragma unroll
      for (int j = 0; j < 4; ++j) {
        const int idx = j * 256 + tid;
        __builtin_amdgcn_global_load_lds(
            (const __attribute__((address_space(1))) void*)
                (Wpkh + (size_t)(s + 1) * 8192 + (size_t)idx * 8),
            (__attribute__((address_space(3))) void*)
                (&Bb[nxt][(size_t)idx * 8]),
            16, 0, 0);
      }
      xa = *(const float4*)(xrow + (s + 1) * KB);
      xb = *(const float4*)(xrow + (s + 1) * KB + 4);
    }
    // ---- compute K-block s (M_rep=2: rows l31 and 32+l31) ----
#pragma unroll
    for (int kk = 0; kk < 2; ++kk) {
      const int u = kk * 2 + kg;
      const short8v ah0 = *(const short8v*)&Ab[cur][l31 * 64        + ((u)     ^ fa) * 8];
      const short8v al0 = *(const short8v*)&Ab[cur][l31 * 64        + ((4 + u) ^ fa) * 8];
      const short8v ah1 = *(const short8v*)&Ab[cur][(32 + l31) * 64 + ((u)     ^ fa) * 8];
      const short8v al1 = *(const short8v*)&Ab[cur][(32 + l31) * 64 + ((4 + u) ^ fa) * 8];
      const short8v bh  = *(const short8v*)&Bb[cur][colB * 64 + ((u)     ^ fb) * 8];
      const short8v bl  = *(const short8v*)&Bb[cur][colB * 64 + ((4 + u) ^ fb) * 8];
      accA = __builtin_amdgcn_mfma_f32_32x32x16_bf16(ah0, bh, accA, 0, 0, 0);
      accA = __builtin_amdgcn_mfma_f32_32x32x16_bf16(ah0, bl, accA, 0, 0, 0);
      accA = __builtin_amdgcn_mfma_f32_32x32x16_bf16(al0, bh, accA, 0, 0, 0);
      accB = __builtin_amdgcn_mfma_f32_32x32x16_bf16(ah1, bh, accB, 0, 0, 0);
      accB = __builtin_amdgcn_mfma_f32_32x32x16_bf16(ah1, bl, accB, 0, 0, 0);
      accB = __builtin_amdgcn_mfma_f32_32x32x16_bf16(al1, bh, accB, 0, 0, 0);
    }
    if (s + 1 < NKBH) {
      short8v hv, lv; ushort h, l;
      bsplit(xa.x, h, l); hv[0] = h; lv[0] = l;
      bsplit(xa.y, h, l); hv[1] = h; lv[1] = l;
      bsplit(xa.z, h, l); hv[2] = h; lv[2] = l;
      bsplit(xa.w, h, l); hv[3] = h; lv[3] = l;
      bsplit(xb.x, h, l); hv[4] = h; lv[4] = l;
      bsplit(xb.y, h, l); hv[5] = h; lv[5] = l;
      bsplit(xb.z, h, l); hv[6] = h; lv[6] = l;
      bsplit(xb.w, h, l); hv[7] = h; lv[7] = l;
      *(short8v*)&Ab[nxt][aoff_h] = hv;
      *(short8v*)&Ab[nxt][aoff_l] = lv;
    }
    __syncthreads();
  }

  // C/D layout (32x32): col = lane&31, row = (reg&3) + 8*(reg>>2) + 4*kg
  float* dst = partials + (size_t)ks * M * 128;
#pragma unroll
  for (int reg = 0; reg < 16; ++reg) {
    const int row = (reg & 3) + 8 * (reg >> 2) + 4 * kg;
    dst[(size_t)(row0 + row) * 128 + colB]      = accA[reg];
    dst[(size_t)(row0 + 32 + row) * 128 + colB] = accB[reg];
  }
}

// one wave per token: fast path; sums the KSPLIT partials inline
__global__ __launch_bounds__(512, 4)
void epi_fast(const float* __restrict__ partials, int M,
              const float* __restrict__ br, const float* __restrict__ bn,
              const float* __restrict__ noise,
              float* __restrict__ out_w, float* __restrict__ out_i,
              float* __restrict__ out_s,
              int* __restrict__ flagcnt, int* __restrict__ flaglist)
{
  const int wid  = threadIdx.x >> 6;
  const int lane = threadIdx.x & 63;
  const int t    = blockIdx.x * 8 + wid;

  const float sr = partials[(size_t)t * 128 + lane]
                 + partials[(size_t)M * 128 + (size_t)t * 128 + lane];
  const float sn = partials[(size_t)t * 128 + 64 + lane]
                 + partials[(size_t)M * 128 + (size_t)t * 128 + 64 + lane];
  const float z  = sn + bn[lane];
  const float sp = fmaxf(z, 0.f) + log1pf(expf(-fabsf(z)));
  const float v  = sr + br[lane] + noise[(size_t)t * NEXP + lane] * sp;

  float m = v;
#pragma unroll
  for (int d = 32; d; d >>= 1) m = fmaxf(m, __shfl_xor(m, d));
  const float p = expf(v - m);
  float sum = p;
#pragma unroll
  for (int d = 32; d; d >>= 1) sum += __shfl_xor(sum, d);
  out_s[(size_t)t * NEXP + lane] = p / sum;

  float cur = v;
  float vals9[9]; int idx9[9];
#pragma unroll
  for (int it = 0; it < 9; ++it) {
    float mx = cur;
#pragma unroll
    for (int d = 32; d; d >>= 1) mx = fmaxf(mx, __shfl_xor(mx, d));
    const unsigned long long b = __ballot(cur == mx);
    const int li = __ffsll(b) - 1;                 // ties -> lowest index
    vals9[it] = mx; idx9[it] = li;
    if (lane == li) cur = -INFINITY;
  }
  bool flagged = false;
#pragma unroll
  for (int q = 0; q < 8; ++q) flagged |= (vals9[q] - vals9[q + 1] < TAU);

  if (flagged) {
    if (lane == 0) {
      const int s = atomicAdd(flagcnt, 1);
      flaglist[s] = t;
    }
    return;                                        // refine_* writes outputs
  }

  float pt[8]; float ws = 0.f;
#pragma unroll
  for (int q = 0; q < 8; ++q) { pt[q] = expf(vals9[q] - m); ws += pt[q]; }
  if (lane < 8) {
    out_w[(size_t)t * 8 + lane] = pt[lane] / ws;
    out_i[(size_t)t * 8 + lane] = (float)idx9[lane];
  }
}

// one WAVE per (flagged token, expert): nf*64 wave-jobs, grid-strided
__global__ __launch_bounds__(512)
void refine_dots(const float* __restrict__ x,
                 const float* __restrict__ Wr, const float* __restrict__ Wn,
                 const float* __restrict__ br, const float* __restrict__ bn,
                 const float* __restrict__ noise,
                 const int* __restrict__ flagcnt, const int* __restrict__ flaglist,
                 double* __restrict__ nv64)
{
  const int nf    = *flagcnt;
  const int lane  = threadIdx.x & 63;
  const int wslot = (blockIdx.x * 512 + threadIdx.x) >> 6;
  const int nwav  = (gridDim.x * 512) >> 6;
  const int total = nf * 64;

  for (int w = wslot; w < total; w += nwav) {
    const int i = w >> 6, e = w & 63;
    const int t = flaglist[i];
    const float* xr  = x  + (size_t)t * KDIM + lane * 4;
    const float* wrr = Wr + (size_t)e * KDIM + lane * 4;
    const float* wnr = Wn + (size_t)e * KDIM + lane * 4;
    double a0 = 0, a1 = 0, c0 = 0, c1 = 0;
#pragma unroll
    for (int q = 0; q < 8; ++q) {
      const float4 xv = *(const float4*)(xr  + q * 256);
      const float4 wv = *(const float4*)(wrr + q * 256);
      const float4 nv = *(const float4*)(wnr + q * 256);
      a0 = fma((double)xv.x, (double)wv.x, a0);
      a1 = fma((double)xv.y, (double)wv.y, a1);
      a0 = fma((double)xv.z, (double)wv.z, a0);
      a1 = fma((double)xv.w, (double)wv.w, a1);
      c0 = fma((double)xv.x, (double)nv.x, c0);
      c1 = fma((double)xv.y, (double)nv.y, c1);
      c0 = fma((double)xv.z, (double)nv.z, c0);
      c1 = fma((double)xv.w, (double)nv.w, c1);
    }
    double ar = a0 + a1, an = c0 + c1;
#pragma unroll
    for (int d = 32; d; d >>= 1) {
      ar += __shfl_xor(ar, d);
      an += __shfl_xor(an, d);
    }
    if (lane == 0) {
      const double rte = ar + (double)br[e];
      const double zz  = an + (double)bn[e];
      const double spd = fmax(zz, 0.0) + log1p(exp(-fabs(zz)));
      nv64[(size_t)i * 64 + e] = rte + (double)noise[(size_t)t * NEXP + e] * spd;
    }
  }
}

// one wave per flagged token: proven fp64 softmax/top-8 tail
__global__ __launch_bounds__(512)
void refine_final(const double* __restrict__ nv64,
                  const int* __restrict__ flagcnt, const int* __restrict__ flaglist,
                  float* __restrict__ out_w, float* __restrict__ out_i,
                  float* __restrict__ out_s)
{
  const int nf    = *flagcnt;
  const int lane  = threadIdx.x & 63;
  const int wslot = (blockIdx.x * 512 + threadIdx.x) >> 6;
  const int nwav  = (gridDim.x * 512) >> 6;

  for (int i = wslot; i < nf; i += nwav) {
    const int t = flaglist[i];
    const double v64 = nv64[(size_t)i * 64 + lane];
    double md = v64;
#pragma unroll
    for (int d = 32; d; d >>= 1) md = fmax(md, __shfl_xor(md, d));
    const double pe = exp(v64 - md);
    double sd = pe;
#pragma unroll
    for (int d = 32; d; d >>= 1) sd += __shfl_xor(sd, d);
    out_s[(size_t)t * NEXP + lane] = (float)(pe / sd);

    double curd = v64;
    double pv8[8]; int pi8[8]; double wsd = 0.0;
#pragma unroll
    for (int it = 0; it < 8; ++it) {
      double mx = curd;
#pragma unroll
      for (int d = 32; d; d >>= 1) mx = fmax(mx, __shfl_xor(mx, d));
      const unsigned long long b = __ballot(curd == mx);
      const int li = __ffsll(b) - 1;
      pv8[it] = __shfl(pe, li); pi8[it] = li; wsd += pv8[it];
      if (lane == li) curd = -1e300;
    }
    if (lane < 8) {
      out_w[(size_t)t * 8 + lane] = (float)(pv8[lane] / wsd);
      out_i[(size_t)t * 8 + lane] = (float)pi8[lane];
    }
  }
}

extern "C" void kernel_launch(void* const* d_in, const int* in_sizes, int n_in,
                              void* d_out, int out_size, void* d_ws, size_t ws_size,
                              hipStream_t stream) {
  const float* x     = (const float*)d_in[0];
  const float* Wr    = (const float*)d_in[1];
  const float* br    = (const float*)d_in[2];
  const float* Wn    = (const float*)d_in[3];
  const float* bn    = (const float*)d_in[4];
  const float* noise = (const float*)d_in[5];

  const int M = in_sizes[0] / KDIM;                  // 16384 tokens
  float*  partials = (float*)d_ws;                   // [2][M][128] f32 = 16 MB
  double* nv64     = (double*)d_ws;                  // aliases partials (dead
                                                     // after epi_fast)
  ushort* Wpk      = (ushort*)(partials + (size_t)KSPLIT * M * 128);  // 1 MB
  int*    flagcnt  = (int*)(Wpk + (size_t)64 * 8192);
  int*    flaglist = flagcnt + 1;                    // up to M ints

  float* out   = (float*)d_out;
  float* out_w = out;                                // [M,8]
  float* out_i = out + (size_t)M * 8;                // [M,8] indices as floats
  float* out_s = out + (size_t)M * 16;               // [M,64]

  convert_w<<<dim3(128), dim3(256), 0, stream>>>(Wr, Wn, Wpk, flagcnt);
  gemm_k1<<<dim3(M / BM, KSPLIT), dim3(256), 0, stream>>>(x, Wpk, partials);
  epi_fast<<<dim3(M / 8), dim3(512), 0, stream>>>(partials, M, br, bn, noise,
                                                  out_w, out_i, out_s,
                                                  flagcnt, flaglist);
  refine_dots<<<dim3(1024), dim3(512), 0, stream>>>(x, Wr, Wn, br, bn, noise,
                                                    flagcnt, flaglist, nv64);
  refine_final<<<dim3(256), dim3(512), 0, stream>>>(nv64, flagcnt, flaglist,
                                                    out_w, out_i, out_s);
}

// Round 19
// 82.931 us; speedup vs baseline: 1.2222x; 1.0207x over previous
//
#include <hip/hip_runtime.h>
#include <math.h>

// NoisyTopkRouter: B=4,S=4096,D=2048,E=64,TOP_K=8
//   gemm_k1: r19 macro-tile: BM=256, 512 thr, KSPLIT=4 (grid 256 = 1 blk/CU).
//   Theory from r13-r18 (six GEMMs all 78-95us): per-step barrier-drain
//   latency is ~constant -> make per-step compute (3200 cyc HBM x-stream)
//   exceed it. Wave = 32 rows x 128 cols. Proven r18 swizzles/numerics.
//   epi_fast sums nsplit partials; refine chain frozen (r12).

#define KDIM 2048
#define NEXP 64
#define BM 256
#define KB 32
#define TAU 1.5e-4f

typedef __attribute__((ext_vector_type(8))) short short8v;
typedef __attribute__((ext_vector_type(16))) float f32x16;

__device__ __forceinline__ void bsplit(float v, ushort& h, ushort& l) {
  unsigned u = __float_as_uint(v);
  unsigned hu = (u + 0x8000u) & 0xFFFF0000u;
  h = (ushort)(hu >> 16);
  float r = v - __uint_as_float(hu);
  l = (ushort)((__float_as_uint(r) + 0x8000u) >> 16);
}

// Wpk[blk 0..63][col 0..127][unit' 0..7][8 bf16]; unit' = (p*4+u) ^ (col&7)
__global__ __launch_bounds__(256)
void convert_w(const float* __restrict__ Wr, const float* __restrict__ Wn,
               ushort* __restrict__ Wpk, int* __restrict__ flagcnt) {
  if (blockIdx.x == 0 && threadIdx.x == 0) *flagcnt = 0;
  const int g = blockIdx.x * 256 + threadIdx.x;   // 32768 threads
  const int col = g >> 8;
  const int rem = g & 255;
  const int blk = rem >> 2;
  const int u   = rem & 3;
  const float* srcrow = (col < NEXP) ? (Wr + (size_t)col * KDIM)
                                     : (Wn + (size_t)(col - NEXP) * KDIM);
  const int k = blk * 32 + u * 8;
  const float4 v0 = *(const float4*)(srcrow + k);
  const float4 v1 = *(const float4*)(srcrow + k + 4);
  short8v hv, lv; ushort h, l;
  bsplit(v0.x, h, l); hv[0] = h; lv[0] = l;
  bsplit(v0.y, h, l); hv[1] = h; lv[1] = l;
  bsplit(v0.z, h, l); hv[2] = h; lv[2] = l;
  bsplit(v0.w, h, l); hv[3] = h; lv[3] = l;
  bsplit(v1.x, h, l); hv[4] = h; lv[4] = l;
  bsplit(v1.y, h, l); hv[5] = h; lv[5] = l;
  bsplit(v1.z, h, l); hv[6] = h; lv[6] = l;
  bsplit(v1.w, h, l); hv[7] = h; lv[7] = l;
  const size_t base = (size_t)blk * 8192 + (size_t)col * 64;
  *(short8v*)(Wpk + base + (size_t)((u)     ^ (col & 7)) * 8) = hv;
  *(short8v*)(Wpk + base + (size_t)((4 + u) ^ (col & 7)) * 8) = lv;
}

__global__ __launch_bounds__(512, 1)
void gemm_k1(const float* __restrict__ x, const ushort* __restrict__ Wpk,
             float* __restrict__ partials, int M)   // [nsplit][M][128]
{
  __shared__ ushort Bb[2][8192];    // 2 x 16KB  [col128][unit'8][8]
  __shared__ ushort Ab[2][16384];   // 2 x 32KB  [row256][unit'8][8]

  const int tid   = threadIdx.x;
  const int row0  = blockIdx.x * BM;
  const int ks    = blockIdx.y;
  const int nspl  = gridDim.y;
  const int kchunk = KDIM / nspl;
  const int NKB   = kchunk / KB;
  const ushort* Wpkh = Wpk + (size_t)ks * NKB * 8192;

  const int wid  = tid >> 6;            // 0..7 row-group (32 rows)
  const int lane = tid & 63;
  const int l31  = lane & 31;
  const int kg   = lane >> 5;

  // A stage map: srow = tid>>1 (0..255), shalf = tid&1 (k 0-15 / 16-31)
  const int srow  = tid >> 1;
  const int shalf = tid & 1;
  const float* xrow = x + (size_t)(row0 + srow) * KDIM + (size_t)ks * kchunk
                        + shalf * 16;
  const int fw = ((srow & 1) << 2) | ((srow >> 1) & 3);
  const int u0 = 2 * shalf;                       // hi units u0, u0+1
  const int aw0 = srow * 64 + ((u0)         ^ fw) * 8;
  const int aw1 = srow * 64 + ((u0 + 1)     ^ fw) * 8;
  const int aw2 = srow * 64 + ((4 + u0)     ^ fw) * 8;
  const int aw3 = srow * 64 + ((5 + u0)     ^ fw) * 8;

  // fragment read constants
  const int rr = wid * 32 + l31;                  // LDS A row
  const int fa = ((l31 & 1) << 2) | ((l31 >> 1) & 3);

  f32x16 acc[4];
#pragma unroll
  for (int c = 0; c < 4; ++c) acc[c] = (f32x16){0,0,0,0,0,0,0,0,0,0,0,0,0,0,0,0};

#define SPLIT16(xq0, xq1, xq2, xq3, buf)                                   \
  do {                                                                     \
    short8v hvA, lvA, hvB, lvB; ushort h, l;                               \
    bsplit(xq0.x, h, l); hvA[0] = h; lvA[0] = l;                           \
    bsplit(xq0.y, h, l); hvA[1] = h; lvA[1] = l;                           \
    bsplit(xq0.z, h, l); hvA[2] = h; lvA[2] = l;                           \
    bsplit(xq0.w, h, l); hvA[3] = h; lvA[3] = l;                           \
    bsplit(xq1.x, h, l); hvA[4] = h; lvA[4] = l;                           \
    bsplit(xq1.y, h, l); hvA[5] = h; lvA[5] = l;                           \
    bsplit(xq1.z, h, l); hvA[6] = h; lvA[6] = l;                           \
    bsplit(xq1.w, h, l); hvA[7] = h; lvA[7] = l;                           \
    bsplit(xq2.x, h, l); hvB[0] = h; lvB[0] = l;                           \
    bsplit(xq2.y, h, l); hvB[1] = h; lvB[1] = l;                           \
    bsplit(xq2.z, h, l); hvB[2] = h; lvB[2] = l;                           \
    bsplit(xq2.w, h, l); hvB[3] = h; lvB[3] = l;                           \
    bsplit(xq3.x, h, l); hvB[4] = h; lvB[4] = l;                           \
    bsplit(xq3.y, h, l); hvB[5] = h; lvB[5] = l;                           \
    bsplit(xq3.z, h, l); hvB[6] = h; lvB[6] = l;                           \
    bsplit(xq3.w, h, l); hvB[7] = h; lvB[7] = l;                           \
    *(short8v*)&Ab[buf][aw0] = hvA;                                        \
    *(short8v*)&Ab[buf][aw1] = hvB;                                        \
    *(short8v*)&Ab[buf][aw2] = lvA;                                        \
    *(short8v*)&Ab[buf][aw3] = lvB;                                        \
  } while (0)

  // prologue: stage step 0
#pragma unroll
  for (int j = 0; j < 2; ++j) {
    const int idx = j * 512 + tid;
    __builtin_amdgcn_global_load_lds(
        (const __attribute__((address_space(1))) void*)(Wpkh + (size_t)idx * 8),
        (__attribute__((address_space(3))) void*)(&Bb[0][(size_t)idx * 8]),
        16, 0, 0);
  }
  {
    const float4 x0 = *(const float4*)(xrow);
    const float4 x1 = *(const float4*)(xrow + 4);
    const float4 x2 = *(const float4*)(xrow + 8);
    const float4 x3 = *(const float4*)(xrow + 12);
    SPLIT16(x0, x1, x2, x3, 0);
  }
  __syncthreads();

  for (int s = 0; s < NKB; ++s) {
    const int cur = s & 1, nxt = cur ^ 1;
    float4 xq0, xq1, xq2, xq3;
    if (s + 1 < NKB) {
#pragma unroll
      for (int j = 0; j < 2; ++j) {
        const int idx = j * 512 + tid;
        __builtin_amdgcn_global_load_lds(
            (const __attribute__((address_space(1))) void*)
                (Wpkh + (size_t)(s + 1) * 8192 + (size_t)idx * 8),
            (__attribute__((address_space(3))) void*)
                (&Bb[nxt][(size_t)idx * 8]), 16, 0, 0);
      }
      xq0 = *(const float4*)(xrow + (s + 1) * KB);
      xq1 = *(const float4*)(xrow + (s + 1) * KB + 4);
      xq2 = *(const float4*)(xrow + (s + 1) * KB + 8);
      xq3 = *(const float4*)(xrow + (s + 1) * KB + 12);
    }
    __builtin_amdgcn_sched_barrier(0);   // pin staging issue before compute

    // ---- compute K-block s: 32 rows x 128 cols per wave ----
#pragma unroll
    for (int kk = 0; kk < 2; ++kk) {
      const int u = kk * 2 + kg;
      const short8v ah = *(const short8v*)&Ab[cur][rr * 64 + ((u)     ^ fa) * 8];
      const short8v al = *(const short8v*)&Ab[cur][rr * 64 + ((4 + u) ^ fa) * 8];
#pragma unroll
      for (int c = 0; c < 4; ++c) {
        const int colB = c * 32 + l31;
        const int fb   = colB & 7;
        const short8v bh = *(const short8v*)&Bb[cur][colB * 64 + ((u)     ^ fb) * 8];
        const short8v bl = *(const short8v*)&Bb[cur][colB * 64 + ((4 + u) ^ fb) * 8];
        acc[c] = __builtin_amdgcn_mfma_f32_32x32x16_bf16(ah, bh, acc[c], 0, 0, 0);
        acc[c] = __builtin_amdgcn_mfma_f32_32x32x16_bf16(ah, bl, acc[c], 0, 0, 0);
        acc[c] = __builtin_amdgcn_mfma_f32_32x32x16_bf16(al, bh, acc[c], 0, 0, 0);
      }
    }

    if (s + 1 < NKB) SPLIT16(xq0, xq1, xq2, xq3, nxt);
    __syncthreads();
  }
#undef SPLIT16

  // C/D layout (32x32): col = lane&31, row = (reg&3) + 8*(reg>>2) + 4*kg
  float* dst = partials + (size_t)ks * M * 128;
#pragma unroll
  for (int c = 0; c < 4; ++c)
#pragma unroll
    for (int reg = 0; reg < 16; ++reg) {
      const int row = (reg & 3) + 8 * (reg >> 2) + 4 * kg;
      dst[(size_t)(row0 + wid * 32 + row) * 128 + c * 32 + l31] = acc[c][reg];
    }
}

// one wave per token: fast path; sums nsplit partials inline
__global__ __launch_bounds__(512, 4)
void epi_fast(const float* __restrict__ partials, int M, int nsplit,
              const float* __restrict__ br, const float* __restrict__ bn,
              const float* __restrict__ noise,
              float* __restrict__ out_w, float* __restrict__ out_i,
              float* __restrict__ out_s,
              int* __restrict__ flagcnt, int* __restrict__ flaglist)
{
  const int wid  = threadIdx.x >> 6;
  const int lane = threadIdx.x & 63;
  const int t    = blockIdx.x * 8 + wid;

  float sr = 0.f, sn = 0.f;
  for (int p = 0; p < nsplit; ++p) {
    sr += partials[(size_t)p * M * 128 + (size_t)t * 128 + lane];
    sn += partials[(size_t)p * M * 128 + (size_t)t * 128 + 64 + lane];
  }
  const float z  = sn + bn[lane];
  const float sp = fmaxf(z, 0.f) + log1pf(expf(-fabsf(z)));
  const float v  = sr + br[lane] + noise[(size_t)t * NEXP + lane] * sp;

  float m = v;
#pragma unroll
  for (int d = 32; d; d >>= 1) m = fmaxf(m, __shfl_xor(m, d));
  const float p = expf(v - m);
  float sum = p;
#pragma unroll
  for (int d = 32; d; d >>= 1) sum += __shfl_xor(sum, d);
  out_s[(size_t)t * NEXP + lane] = p / sum;

  float cur = v;
  float vals9[9]; int idx9[9];
#pragma unroll
  for (int it = 0; it < 9; ++it) {
    float mx = cur;
#pragma unroll
    for (int d = 32; d; d >>= 1) mx = fmaxf(mx, __shfl_xor(mx, d));
    const unsigned long long b = __ballot(cur == mx);
    const int li = __ffsll(b) - 1;                 // ties -> lowest index
    vals9[it] = mx; idx9[it] = li;
    if (lane == li) cur = -INFINITY;
  }
  bool flagged = false;
#pragma unroll
  for (int q = 0; q < 8; ++q) flagged |= (vals9[q] - vals9[q + 1] < TAU);

  if (flagged) {
    if (lane == 0) {
      const int s = atomicAdd(flagcnt, 1);
      flaglist[s] = t;
    }
    return;                                        // refine_* writes outputs
  }

  float pt[8]; float ws = 0.f;
#pragma unroll
  for (int q = 0; q < 8; ++q) { pt[q] = expf(vals9[q] - m); ws += pt[q]; }
  if (lane < 8) {
    out_w[(size_t)t * 8 + lane] = pt[lane] / ws;
    out_i[(size_t)t * 8 + lane] = (float)idx9[lane];
  }
}

// one WAVE per (flagged token, expert): nf*64 wave-jobs, grid-strided
__global__ __launch_bounds__(512)
void refine_dots(const float* __restrict__ x,
                 const float* __restrict__ Wr, const float* __restrict__ Wn,
                 const float* __restrict__ br, const float* __restrict__ bn,
                 const float* __restrict__ noise,
                 const int* __restrict__ flagcnt, const int* __restrict__ flaglist,
                 double* __restrict__ nv64)
{
  const int nf    = *flagcnt;
  const int lane  = threadIdx.x & 63;
  const int wslot = (blockIdx.x * 512 + threadIdx.x) >> 6;
  const int nwav  = (gridDim.x * 512) >> 6;
  const int total = nf * 64;

  for (int w = wslot; w < total; w += nwav) {
    const int i = w >> 6, e = w & 63;
    const int t = flaglist[i];
    const float* xr  = x  + (size_t)t * KDIM + lane * 4;
    const float* wrr = Wr + (size_t)e * KDIM + lane * 4;
    const float* wnr = Wn + (size_t)e * KDIM + lane * 4;
    double a0 = 0, a1 = 0, c0 = 0, c1 = 0;
#pragma unroll
    for (int q = 0; q < 8; ++q) {
      const float4 xv = *(const float4*)(xr  + q * 256);
      const float4 wv = *(const float4*)(wrr + q * 256);
      const float4 nv = *(const float4*)(wnr + q * 256);
      a0 = fma((double)xv.x, (double)wv.x, a0);
      a1 = fma((double)xv.y, (double)wv.y, a1);
      a0 = fma((double)xv.z, (double)wv.z, a0);
      a1 = fma((double)xv.w, (double)wv.w, a1);
      c0 = fma((double)xv.x, (double)nv.x, c0);
      c1 = fma((double)xv.y, (double)nv.y, c1);
      c0 = fma((double)xv.z, (double)nv.z, c0);
      c1 = fma((double)xv.w, (double)nv.w, c1);
    }
    double ar = a0 + a1, an = c0 + c1;
#pragma unroll
    for (int d = 32; d; d >>= 1) {
      ar += __shfl_xor(ar, d);
      an += __shfl_xor(an, d);
    }
    if (lane == 0) {
      const double rte = ar + (double)br[e];
      const double zz  = an + (double)bn[e];
      const double spd = fmax(zz, 0.0) + log1p(exp(-fabs(zz)));
      nv64[(size_t)i * 64 + e] = rte + (double)noise[(size_t)t * NEXP + e] * spd;
    }
  }
}

// one wave per flagged token: proven fp64 softmax/top-8 tail
__global__ __launch_bounds__(512)
void refine_final(const double* __restrict__ nv64,
                  const int* __restrict__ flagcnt, const int* __restrict__ flaglist,
                  float* __restrict__ out_w, float* __restrict__ out_i,
                  float* __restrict__ out_s)
{
  const int nf    = *flagcnt;
  const int lane  = threadIdx.x & 63;
  const int wslot = (blockIdx.x * 512 + threadIdx.x) >> 6;
  const int nwav  = (gridDim.x * 512) >> 6;

  for (int i = wslot; i < nf; i += nwav) {
    const int t = flaglist[i];
    const double v64 = nv64[(size_t)i * 64 + lane];
    double md = v64;
#pragma unroll
    for (int d = 32; d; d >>= 1) md = fmax(md, __shfl_xor(md, d));
    const double pe = exp(v64 - md);
    double sd = pe;
#pragma unroll
    for (int d = 32; d; d >>= 1) sd += __shfl_xor(sd, d);
    out_s[(size_t)t * NEXP + lane] = (float)(pe / sd);

    double curd = v64;
    double pv8[8]; int pi8[8]; double wsd = 0.0;
#pragma unroll
    for (int it = 0; it < 8; ++it) {
      double mx = curd;
#pragma unroll
      for (int d = 32; d; d >>= 1) mx = fmax(mx, __shfl_xor(mx, d));
      const unsigned long long b = __ballot(curd == mx);
      const int li = __ffsll(b) - 1;
      pv8[it] = __shfl(pe, li); pi8[it] = li; wsd += pv8[it];
      if (lane == li) curd = -1e300;
    }
    if (lane < 8) {
      out_w[(size_t)t * 8 + lane] = (float)(pv8[lane] / wsd);
      out_i[(size_t)t * 8 + lane] = (float)pi8[lane];
    }
  }
}

extern "C" void kernel_launch(void* const* d_in, const int* in_sizes, int n_in,
                              void* d_out, int out_size, void* d_ws, size_t ws_size,
                              hipStream_t stream) {
  const float* x     = (const float*)d_in[0];
  const float* Wr    = (const float*)d_in[1];
  const float* br    = (const float*)d_in[2];
  const float* Wn    = (const float*)d_in[3];
  const float* bn    = (const float*)d_in[4];
  const float* noise = (const float*)d_in[5];

  const int M = in_sizes[0] / KDIM;                  // 16384 tokens

  // KSPLIT=4 (grid 256 = 1 block/CU) if workspace allows; else 2.
  const size_t need4 = (size_t)4 * M * 128 * 4 + (1 << 20) + ((size_t)M + 1) * 4;
  const int nsplit = (ws_size >= need4) ? 4 : 2;

  float*  partials = (float*)d_ws;                   // [nsplit][M][128]
  double* nv64     = (double*)d_ws;                  // aliases (dead after epi)
  ushort* Wpk      = (ushort*)(partials + (size_t)nsplit * M * 128);  // 1 MB
  int*    flagcnt  = (int*)(Wpk + (size_t)64 * 8192);
  int*    flaglist = flagcnt + 1;

  float* out   = (float*)d_out;
  float* out_w = out;                                // [M,8]
  float* out_i = out + (size_t)M * 8;                // [M,8] indices as floats
  float* out_s = out + (size_t)M * 16;               // [M,64]

  convert_w<<<dim3(128), dim3(256), 0, stream>>>(Wr, Wn, Wpk, flagcnt);
  gemm_k1<<<dim3(M / BM, nsplit), dim3(512), 0, stream>>>(x, Wpk, partials, M);
  epi_fast<<<dim3(M / 8), dim3(512), 0, stream>>>(partials, M, nsplit, br, bn,
                                                  noise, out_w, out_i, out_s,
                                                  flagcnt, flaglist);
  refine_dots<<<dim3(1024), dim3(512), 0, stream>>>(x, Wr, Wn, br, bn, noise,
                                                    flagcnt, flaglist, nv64);
  refine_final<<<dim3(256), dim3(512), 0, stream>>>(nv64, flagcnt, flaglist,
                                                    out_w, out_i, out_s);
}